// Round 9
// baseline (6286.295 us; speedup 1.0000x reference)
//
#include <hip/hip_runtime.h>

#define HW 4096
#define NC 512
#define NP 100
#define NPH 50
#define NB 16
#define GAMMA 10.0f

// ws layout (floats):
// [0, 51200)        Wp (normalized proxies, [c][p])
// [51200, 51328)    accums: [0]=num_pos,[1]=num_neg,[2]=sum_t,[3]=reg_sum,[8..108)=grm

__global__ void k_norm_proxies(const float* __restrict__ pp, float* __restrict__ Wp) {
    int p = blockIdx.x;      // 0..99
    int t = threadIdx.x;     // 0..63 (one wave)
    float s = 0.f;
    for (int c = t; c < NC; c += 64) { float v = pp[c * NP + p]; s += v * v; }
    #pragma unroll
    for (int off = 32; off > 0; off >>= 1) s += __shfl_down(s, off);
    s = __shfl(s, 0);
    float inv = 1.0f / sqrtf(s + 1e-12f);
    for (int c = t; c < NC; c += 64) Wp[c * NP + p] = pp[c * NP + p] * inv;
}

// loss_reg via identity: sum_{p!=q} (Wp^T Wp)[p,q] = sum_c (sum_p w_cp)^2 - sum_{c,p} w_cp^2
__global__ void k_reg2(const float* __restrict__ Wp, float* __restrict__ accums) {
    __shared__ float wsum[8];
    int tid = threadIdx.x;           // 512 threads, one per c
    const float4* r = reinterpret_cast<const float4*>(Wp + tid * NP);
    float s = 0.f, ss = 0.f;
    #pragma unroll
    for (int j = 0; j < 25; ++j) {
        float4 v = r[j];
        s  += v.x + v.y + v.z + v.w;
        ss += v.x * v.x + v.y * v.y + v.z * v.z + v.w * v.w;
    }
    float contrib = s * s - ss;
    #pragma unroll
    for (int off = 32; off > 0; off >>= 1) contrib += __shfl_xor(contrib, off);
    if ((tid & 63) == 0) wsum[tid >> 6] = contrib;
    __syncthreads();
    if (tid == 0) {
        float tot = 0.f;
        #pragma unroll
        for (int i = 0; i < 8; ++i) tot += wsum[i];
        accums[3] = tot;
    }
}

// Process 8 c's: each thread dots against its 50-proxy slice (float2 LDS broadcasts).
__device__ __forceinline__ void proc8(const float (&xr)[8], const float (&gr)[8],
                                      const float* wbase, float (&acc)[NPH],
                                      float& sxx, float& sgg, float& sxg) {
    #pragma unroll
    for (int i = 0; i < 8; ++i) {
        float xv = xr[i], gv = gr[i];
        sxx = fmaf(xv, xv, sxx);
        sgg = fmaf(gv, gv, sgg);
        sxg = fmaf(xv, gv, sxg);
        const float2* wrow = reinterpret_cast<const float2*>(wbase + i * NP);  // 8B-aligned (pi*50 even)
        #pragma unroll
        for (int q = 0; q < 25; ++q) {
            float2 w2 = wrow[q];
            acc[2*q+0] = fmaf(xv, w2.x, acc[2*q+0]);
            acc[2*q+1] = fmaf(xv, w2.y, acc[2*q+1]);
        }
    }
}

// 256 threads/block = 128 points x 2 P-halves. pi = tid>>7 owns proxies [pi*50, pi*50+50).
// Every thread walks all 512 c's -> acc[50] only; live state ~110 VGPR, fits the 128
// budget the allocator insists on (rounds 3/5/6: acc[100] spilled 11.8 GB to scratch).
__global__ __launch_bounds__(256, 4)
void k_main(
        const float* __restrict__ x, const float* __restrict__ xgt,
        const float* __restrict__ t, const float* __restrict__ ha,
        const float* __restrict__ Wp, float* __restrict__ accums) {
    // wlds: [64][100] Wp segment (6400 floats) during main loop; then [128][51]
    // exchange buffer (stride 51 -> 2 lanes/bank, conflict-free) for pi=1's acc.
    __shared__ __align__(16) float wlds[6528];   // 26.1 KB
    __shared__ float grmLDS[NP];
    __shared__ float scal[3];

    int tid  = threadIdx.x;
    int pi   = tid >> 7;            // P-half: 0 or 1
    int hidx = tid & 127;           // point index within block
    int point = blockIdx.x * 128 + hidx;   // 65536 points
    int b = point >> 12;            // blocks never straddle b (4096/128=32)
    int n = point & (HW - 1);

    if (tid < NP) grmLDS[tid] = 0.f;
    if (tid < 3)  scal[tid]  = 0.f;

    // t-flag (pi=0 only; used only in epilogue)
    float tf = 0.f;
    if (pi == 0) {
        int h = n >> 6, w = n & 63;
        const float* tb = t + (size_t)b * (256 * 256) + (h * 4) * 256 + w * 4;
        float ts = 0.f;
        #pragma unroll
        for (int i = 0; i < 4; ++i) {
            float4 v = *reinterpret_cast<const float4*>(tb + i * 256);
            ts += v.x + v.y + v.z + v.w;
        }
        tf = (ts * (1.0f / 16.0f) > 0.02f) ? 1.0f : 0.0f;
    }

    const float* xp = x   + (size_t)b * (NC * HW) + n;
    const float* gp = xgt + (size_t)b * (NC * HW) + n;

    float acc[NPH];
    #pragma unroll
    for (int p = 0; p < NPH; ++p) acc[p] = 0.f;
    float sxx = 0.f, sgg = 0.f, sxg = 0.f;

    // 64 chunks of 8 c's per thread (all 512 c), register double-buffered prefetch
    float xa[8], ga[8], xb[8], gb[8];
    #pragma unroll
    for (int i = 0; i < 8; ++i) { xa[i] = xp[(size_t)i * HW]; ga[i] = gp[(size_t)i * HW]; }

    float4* wl4 = reinterpret_cast<float4*>(wlds);

    for (int seg = 0; seg < 8; ++seg) {
        __syncthreads();   // previous segment fully consumed
        const float4* ws4 = reinterpret_cast<const float4*>(Wp + seg * 64 * NP);
        #pragma unroll
        for (int j = 0; j < 6; ++j) wl4[tid + j * 256] = ws4[tid + j * 256];
        if (tid < 64) wl4[1536 + tid] = ws4[1536 + tid];
        __syncthreads();

        #pragma unroll
        for (int cc = 0; cc < 8; cc += 2) {
            int k = seg * 8 + cc;            // 0..62
            {   // prefetch chunk k+1 (k+1 <= 63, always valid)
                const float* xc = xp + (size_t)(k + 1) * 8 * HW;
                const float* gc = gp + (size_t)(k + 1) * 8 * HW;
                #pragma unroll
                for (int i = 0; i < 8; ++i) { xb[i] = xc[(size_t)i * HW]; gb[i] = gc[(size_t)i * HW]; }
            }
            proc8(xa, ga, wlds + (cc * 8) * NP + pi * NPH, acc, sxx, sgg, sxg);
            if (k + 2 < 64) {
                const float* xc = xp + (size_t)(k + 2) * 8 * HW;
                const float* gc = gp + (size_t)(k + 2) * 8 * HW;
                #pragma unroll
                for (int i = 0; i < 8; ++i) { xa[i] = xc[(size_t)i * HW]; ga[i] = gc[(size_t)i * HW]; }
            }
            proc8(xb, gb, wlds + ((cc + 1) * 8) * NP + pi * NPH, acc, sxx, sgg, sxg);
        }
    }

    // ---- exchange pi=1's 50 dots through LDS ----
    __syncthreads();                 // everyone done with wlds-as-Wp
    if (pi == 1) {
        float* dst = wlds + hidx * 51;
        #pragma unroll
        for (int j = 0; j < NPH; ++j) dst[j] = acc[j];
    }
    __syncthreads();

    if (pi == 0) {
        float invx = 1.0f / sqrtf(sxx + 1e-12f);
        float* src = wlds + hidx * 51;    // other half's raw dots

        // pass 1: scale own half in place, find max over all 100
        float m = -1e30f;
        #pragma unroll
        for (int p = 0; p < NPH; ++p) { acc[p] *= invx; m = fmaxf(m, acc[p]); }
        #pragma unroll
        for (int p = 0; p < NPH; ++p) m = fmaxf(m, src[p] * invx);

        // pass 2: exp, denom, weighted sum; stash other-half exps back into src
        float s = 0.f, sf = 0.f;
        #pragma unroll
        for (int p = 0; p < NPH; ++p) {
            float ev = __expf(GAMMA * (acc[p] - m));
            s += ev; sf = fmaf(ev, acc[p], sf);
            acc[p] = ev;
        }
        #pragma unroll
        for (int p = 0; p < NPH; ++p) {
            float v  = src[p] * invx;
            float ev = __expf(GAMMA * (v - m));
            s += ev; sf = fmaf(ev, v, sf);
            src[p] = ev;                  // own row, no race
        }
        float Sim   = sf / s;
        float invg  = 1.0f / sqrtf(sgg + 1e-12f);
        float cosgt = sxg * invx * invg;

        int lane = tid & 63;
        float v0 = (1.0f - Sim)   * (1.0f - tf);
        float v1 = (1.0f - cosgt) * tf;
        float v2 = tf;
        #pragma unroll
        for (int off = 32; off > 0; off >>= 1) {
            v0 += __shfl_xor(v0, off);
            v1 += __shfl_xor(v1, off);
            v2 += __shfl_xor(v2, off);
        }
        if (lane == 0) {
            atomicAdd(&scal[0], v0);
            atomicAdd(&scal[1], v1);
            atomicAdd(&scal[2], v2);
        }
        float winv = (1.0f - ha[b]) / s;
        #pragma unroll
        for (int p = 0; p < NPH; ++p) {
            float g = acc[p] * winv;
            #pragma unroll
            for (int off = 32; off > 0; off >>= 1) g += __shfl_xor(g, off);
            if (lane == 0) atomicAdd(&grmLDS[p], g);
        }
        #pragma unroll
        for (int p = 0; p < NPH; ++p) {
            float g = src[p] * winv;
            #pragma unroll
            for (int off = 32; off > 0; off >>= 1) g += __shfl_xor(g, off);
            if (lane == 0) atomicAdd(&grmLDS[NPH + p], g);
        }
    }
    __syncthreads();
    if (tid < NP) atomicAdd(&accums[8 + tid], grmLDS[tid]);
    if (tid < 3)  atomicAdd(&accums[tid], scal[tid]);
}

__global__ void k_final(const float* __restrict__ accums, const float* __restrict__ ha,
                        const float* __restrict__ gr, float* __restrict__ out) {
    __shared__ float red;
    int t = threadIdx.x;    // 128
    if (t == 0) red = 0.f;
    __syncthreads();
    float S = 0.f;
    #pragma unroll
    for (int b2 = 0; b2 < NB; ++b2) S += 1.0f - ha[b2];
    float contrib = 0.f;
    if (t < NP) {
        float g = accums[8 + t] / (4096.0f * (S + 1e-12f));
        contrib = fabsf(g - gr[t]);
    }
    atomicAdd(&red, contrib);
    __syncthreads();
    if (t == 0) {
        float num_pos = accums[0], num_neg = accums[1], sum_t = accums[2], reg = accums[3];
        float den_pos = (float)(NB * HW) - sum_t;
        float loss_pos = num_pos / (den_pos + 1e-12f);
        float loss_neg = num_neg / (sum_t + 1e-12f);
        float loss_reg = reg / (float)(NP * NP);
        float loss_glob = red / (float)NP;
        out[0] = loss_pos + loss_neg + 0.1f * loss_reg + loss_glob;
    }
}

extern "C" void kernel_launch(void* const* d_in, const int* in_sizes, int n_in,
                              void* d_out, int out_size, void* d_ws, size_t ws_size,
                              hipStream_t stream) {
    const float* x   = (const float*)d_in[0];
    const float* xgt = (const float*)d_in[1];
    const float* t   = (const float*)d_in[2];
    // d_in[3] = ds (int scalar, fixed = 4)
    const float* ha  = (const float*)d_in[4];
    const float* pp  = (const float*)d_in[5];
    const float* gr  = (const float*)d_in[6];
    float* out = (float*)d_out;

    float* Wp     = (float*)d_ws;
    float* accums = Wp + 51200;

    hipMemsetAsync(accums, 0, 128 * sizeof(float), stream);
    k_norm_proxies<<<100, 64, 0, stream>>>(pp, Wp);
    k_reg2<<<1, 512, 0, stream>>>(Wp, accums);
    k_main<<<512, 256, 0, stream>>>(x, xgt, t, ha, Wp, accums);
    k_final<<<1, 128, 0, stream>>>(accums, ha, gr, out);
}